// Round 1
// baseline (881.894 us; speedup 1.0000x reference)
//
#include <hip/hip_runtime.h>

// Problem constants: T=32768 tokens, H=2048 hidden, I=768 intermediate
#define T_TOK 32768
#define H_DIM 2048
#define I_DIM 768
#define N1_DIM 1536   // 2*I

typedef unsigned short ushort_t;
typedef __attribute__((ext_vector_type(8))) short  short8;   // 8 bf16 = 4 VGPRs (MFMA A/B frag)
typedef __attribute__((ext_vector_type(4))) float  floatx4;  // MFMA C/D frag

// ---- bf16 helpers (raw-bit, RNE) ----
__device__ __forceinline__ ushort_t f2bf(float f) {
    union { float f; unsigned u; } v; v.f = f;
    unsigned u = v.u;
    unsigned r = (u + 0x7fffu + ((u >> 16) & 1u)) >> 16;
    return (ushort_t)r;
}
__device__ __forceinline__ float bf2f(ushort_t h) {
    union { unsigned u; float f; } v; v.u = ((unsigned)h) << 16;
    return v.f;
}

// ---- async global->LDS, 16B per lane (dest = wave-uniform base + lane*16) ----
typedef __attribute__((address_space(1))) const void gq_t;
typedef __attribute__((address_space(3))) void lq_t;
__device__ __forceinline__ void gld_lds16(const void* g, void* l) {
    __builtin_amdgcn_global_load_lds((gq_t*)g, (lq_t*)l, 16, 0, 0);
}

// =====================================================================
// cast fp32 -> bf16, 8 elems/thread (grid*256*8 == n exactly)
// =====================================================================
__global__ __launch_bounds__(256) void cast_f32_bf16_k(
    const float* __restrict__ in, ushort_t* __restrict__ out)
{
    size_t i = ((size_t)blockIdx.x * 256 + threadIdx.x) * 8;
    const float4 a = *(const float4*)(in + i);
    const float4 b = *(const float4*)(in + i + 4);
    short8 o;
    o[0] = (short)f2bf(a.x); o[1] = (short)f2bf(a.y);
    o[2] = (short)f2bf(a.z); o[3] = (short)f2bf(a.w);
    o[4] = (short)f2bf(b.x); o[5] = (short)f2bf(b.y);
    o[6] = (short)f2bf(b.z); o[7] = (short)f2bf(b.w);
    *(short8*)(out + i) = o;
}

// =====================================================================
// transpose + cast: in fp32 [R][C] -> out bf16 [C][R]   (R,C multiples of 32)
// =====================================================================
__global__ __launch_bounds__(256) void transpose_cast_k(
    const float* __restrict__ in, ushort_t* __restrict__ out, int R, int C)
{
    __shared__ float tile[32][33];
    const int c0 = blockIdx.x * 32;
    const int r0 = blockIdx.y * 32;
    const int tx = threadIdx.x;   // 0..31
    const int ty = threadIdx.y;   // 0..7
#pragma unroll
    for (int dy = 0; dy < 32; dy += 8)
        tile[ty + dy][tx] = in[(size_t)(r0 + ty + dy) * C + (c0 + tx)];
    __syncthreads();
#pragma unroll
    for (int dy = 0; dy < 32; dy += 8)
        out[(size_t)(c0 + ty + dy) * R + (r0 + tx)] = f2bf(tile[tx][ty + dy]);
}

// =====================================================================
// bf16 GEMM, C = A @ Bt^T.
//   A  : [M][lda] bf16, row-major, k contiguous
//   Bt : [N][ldb] bf16, row-major (pre-transposed weight), k contiguous
//   C  : [M][ldc], bf16 or fp32 per template
// 128x128 tile, BK=64, 256 threads (4 waves, each 64x64 = 4x4 MFMA tiles).
// XOR-swizzled k-groups: LDS[r][slot g] holds global k-group (g ^ (r&7)),
// applied identically in staging and frag reads -> 2-way banks (free).
// =====================================================================
template <bool BF16_OUT>
__global__ __launch_bounds__(256) void gemm_bt(
    const ushort_t* __restrict__ A, int lda,
    const ushort_t* __restrict__ Bt, int ldb,
    void* __restrict__ Cv, int ldc, int K)
{
    __shared__ ushort_t Asm[128 * 64];
    __shared__ ushort_t Bsm[128 * 64];

    const int tid  = threadIdx.x;
    const int lane = tid & 63;
    const int wave = tid >> 6;
    const int m0   = blockIdx.x * 128;
    const int n0   = blockIdx.y * 128;
    const int wm   = (wave >> 1) * 64;   // wave origin within tile
    const int wn   = (wave & 1) * 64;
    const int s    = lane & 15;          // MFMA row/col within 16
    const int q    = lane >> 4;          // MFMA quad
    const int s7   = s & 7;

    // staging geometry: chunk = 8 rows x 64 k; lane covers (row=lane>>3, kgroup=(lane&7)^row)
    const int srow = lane >> 3;
    const int skof = ((lane & 7) ^ srow) * 8;

    floatx4 acc[4][4];
#pragma unroll
    for (int i = 0; i < 4; ++i)
#pragma unroll
        for (int j = 0; j < 4; ++j)
            acc[i][j] = floatx4{0.f, 0.f, 0.f, 0.f};

    for (int kt = 0; kt < K; kt += 64) {
#pragma unroll
        for (int c = 0; c < 4; ++c) {
            const int ca = wave + c * 4;  // chunk 0..15
            gld_lds16(A  + (size_t)(m0 + ca * 8 + srow) * lda + kt + skof, &Asm[ca * 512]);
            gld_lds16(Bt + (size_t)(n0 + ca * 8 + srow) * ldb + kt + skof, &Bsm[ca * 512]);
        }
        __syncthreads();
#pragma unroll
        for (int ks = 0; ks < 2; ++ks) {
            const int slot = ((ks * 4 + q) ^ s7) * 8;  // swizzled 8-elem k-group
            short8 av[4], bv[4];
#pragma unroll
            for (int i = 0; i < 4; ++i) {
                av[i] = *(const short8*)&Asm[(wm + i * 16 + s) * 64 + slot];
                bv[i] = *(const short8*)&Bsm[(wn + i * 16 + s) * 64 + slot];
            }
#pragma unroll
            for (int i = 0; i < 4; ++i)
#pragma unroll
                for (int j = 0; j < 4; ++j)
                    acc[i][j] = __builtin_amdgcn_mfma_f32_16x16x32_bf16(
                        av[i], bv[j], acc[i][j], 0, 0, 0);
        }
        __syncthreads();
    }

    // epilogue: C/D layout col = lane&15, row = quad*4 + reg  (m89-verified)
    const int cr = q * 4;
#pragma unroll
    for (int i = 0; i < 4; ++i) {
#pragma unroll
        for (int j = 0; j < 4; ++j) {
            const int r  = m0 + wm + i * 16 + cr;
            const int cn = n0 + wn + j * 16 + s;
#pragma unroll
            for (int t = 0; t < 4; ++t) {
                const float v = acc[i][j][t];
                if (BF16_OUT)
                    ((ushort_t*)Cv)[(size_t)(r + t) * ldc + cn] = f2bf(v);
                else
                    ((float*)Cv)[(size_t)(r + t) * ldc + cn] = v;
            }
        }
    }
}

// =====================================================================
// x[t][i] = silu(gu[t][i]) * gu[t][768+i], bf16 in/out, 8 elems/thread
// =====================================================================
__global__ __launch_bounds__(256) void silu_mul_k(
    const ushort_t* __restrict__ gu, ushort_t* __restrict__ x)
{
    const int idx = blockIdx.x * 256 + threadIdx.x;  // < T*96
    const int t   = idx / 96;
    const int c8  = (idx - t * 96) * 8;
    const short8 gv = *(const short8*)(gu + (size_t)t * N1_DIM + c8);
    const short8 uv = *(const short8*)(gu + (size_t)t * N1_DIM + I_DIM + c8);
    short8 xv;
#pragma unroll
    for (int e = 0; e < 8; ++e) {
        const float g = bf2f((ushort_t)gv[e]);
        const float u = bf2f((ushort_t)uv[e]);
        const float s = g / (1.0f + __expf(-g));
        xv[e] = (short)f2bf(s * u);
    }
    *(short8*)(x + (size_t)t * I_DIM + c8) = xv;
}

// =====================================================================
extern "C" void kernel_launch(void* const* d_in, const int* in_sizes, int n_in,
                              void* d_out, int out_size, void* d_ws, size_t ws_size,
                              hipStream_t stream)
{
    const float* hs  = (const float*)d_in[0];  // [32768][2048]
    const float* wgu = (const float*)d_in[1];  // [2048][1536]
    const float* wd  = (const float*)d_in[2];  // [768][2048]
    float*       out = (float*)d_out;          // [32768][2048] fp32

    // workspace layout (bytes): wgu_t | wd_t | x
    char* ws = (char*)d_ws;
    ushort_t* wgu_t = (ushort_t*)ws;                          // [1536][2048] bf16, 6291456 B
    ushort_t* wd_t  = (ushort_t*)(ws + 6291456);              // [2048][768]  bf16, 3145728 B
    ushort_t* xb    = (ushort_t*)(ws + 9437184);              // [32768][768] bf16, 50331648 B

    // d_out doubles as scratch (stream-ordered; GEMM2 overwrites everything):
    //   [0, 100663296)          gate_up bf16 [32768][1536]
    //   [100663296, 234881024)  X bf16 [32768][2048]
    char* ob = (char*)d_out;
    ushort_t* gu_s = (ushort_t*)ob;
    ushort_t* hs_b = (ushort_t*)(ob + 100663296);

    // 1. cast activations fp32->bf16 (67.1M elems = 32768 blocks * 256 thr * 8)
    cast_f32_bf16_k<<<32768, 256, 0, stream>>>(hs, hs_b);
    // 2. transpose-cast weights to [N][K] bf16
    transpose_cast_k<<<dim3(N1_DIM / 32, H_DIM / 32), dim3(32, 8), 0, stream>>>(
        wgu, wgu_t, H_DIM, N1_DIM);
    transpose_cast_k<<<dim3(H_DIM / 32, I_DIM / 32), dim3(32, 8), 0, stream>>>(
        wd, wd_t, I_DIM, H_DIM);
    // 3. GEMM1: gate_up = X @ Wgu   [32768][1536]
    gemm_bt<true><<<dim3(T_TOK / 128, N1_DIM / 128), 256, 0, stream>>>(
        hs_b, H_DIM, wgu_t, H_DIM, (void*)gu_s, N1_DIM, H_DIM);
    // 4. x = silu(gate) * up        [32768][768]
    silu_mul_k<<<(T_TOK * (I_DIM / 8)) / 256, 256, 0, stream>>>(gu_s, xb);
    // 5. GEMM2: out = x @ Wd        [32768][2048] fp32
    gemm_bt<false><<<dim3(T_TOK / 128, H_DIM / 128), 256, 0, stream>>>(
        xb, I_DIM, wd_t, I_DIM, (void*)out, H_DIM, I_DIM);
}